// Round 1
// 242.004 us; speedup vs baseline: 1.1011x; 1.1011x over previous
//
#include <hip/hip_runtime.h>

// SparseMSDeformableAttention MI355X — round 9.
// r8 post-mortem: sample_k (95us) is gather-line-bound (f32 128B segments, 8x XCD-
// duplicated v fetch: FETCH 227MB); GEMMs grid-starved (832 blocks = 3.25/CU) with
// 6 launch boundaries.
//  - vproj now bf16 (gemm1 epilogue converts): halves gather lines + HBM dup.
//  - gemm2+gemm3 fused (contiguous WoWa, N=384, out stride 384); that fused with
//    gemm1 via gridDim.z=2 -> one launch, 2080 active blocks.
//  - XCD-bijective swizzle on GEMM grids: same-A-panel tiles share one XCD L2.
//  - fixed latent OOB: W_off is 65536 elems (old cvt converted 131072).
// Workspace: vproj bf16 | oa f32[NTOK][384] | q_bf(=outpre overlay) | v_bf | weights
// = 82.14 MB (previous layout used 82.3).

#define LQ    13294
#define NTOK  26588
#define CHUNK 3324        // ceil(NTOK/8) for XCD swizzle
#define NE    6806528     // NTOK*256

typedef unsigned short ushort_t;
typedef __attribute__((ext_vector_type(8))) short short8;
typedef __attribute__((ext_vector_type(4))) float float4_t;
typedef __attribute__((ext_vector_type(2))) unsigned int uint2_t;

__device__ __forceinline__ ushort_t f2b(float f) {
    unsigned int x = __float_as_uint(f);
    return (ushort_t)((x + 0x7fffu + ((x >> 16) & 1u)) >> 16);   // RNE
}

// ---------------- bulk f32 -> bf16 convert ----------------
__device__ __forceinline__ void cvt_seg(const float* __restrict__ s,
                                        ushort_t* __restrict__ d,
                                        int n4, int gid, int stride) {
    const float4_t* s4 = (const float4_t*)s;
    for (int i = gid; i < n4; i += stride) {
        float4_t f = s4[i];
        ushort4 o;
        o.x = f2b(f.x); o.y = f2b(f.y); o.z = f2b(f.z); o.w = f2b(f.w);
        *(ushort4*)(d + (long)i * 4) = o;
    }
}

__global__ __launch_bounds__(256) void cvt_k(
    const float* q, const float* v, const float* Wv, const float* Wo,
    const float* Wa, const float* Wout,
    ushort_t* q_bf, ushort_t* v_bf, ushort_t* Wv_bf, ushort_t* WoWa_bf,
    ushort_t* Wout_bf)
{
    const int gid = blockIdx.x * 256 + threadIdx.x;
    const int stride = gridDim.x * 256;
    cvt_seg(q,    q_bf,            NE / 4,     gid, stride);
    cvt_seg(v,    v_bf,            NE / 4,     gid, stride);
    cvt_seg(Wv,   WoWa_bf ? Wv_bf : Wv_bf, 65536 / 4, gid, stride);
    cvt_seg(Wo,   WoWa_bf,         65536 / 4,  gid, stride);   // rows 0..255 of WoWa
    cvt_seg(Wa,   WoWa_bf + 65536, 32768 / 4,  gid, stride);   // rows 256..383
    cvt_seg(Wout, Wout_bf,         65536 / 4,  gid, stride);
}

// ---------------- shared bf16 MFMA tile body (r7-validated fragment maps) ----------
// 256 threads = 4 waves; tile 128(M) x 64(N), K-tile 32; LDS row stride 40 ushorts.
// A[m=ln&15][k=(ln>>4)*8+j]; B-op = W[n=ln&15][same k];
// D col=ln&15 (n), row=(ln>>4)*4+r (m).
__device__ __forceinline__ void gemm_tile(
    const ushort_t* __restrict__ A,     // [M][256] bf16
    const ushort_t* __restrict__ W,     // [>=n0+64][256] bf16
    int m0, int n0, int M,
    ushort_t* As, ushort_t* Bs, float4_t acc[2][4])
{
    const int tid = threadIdx.x;
    const int w  = tid >> 6;
    const int ln = tid & 63;
    const int sr = tid >> 2;            // staging row 0..63
    const int sc = (tid & 3) * 8;       // staging col {0,8,16,24}

    for (int k0 = 0; k0 < 256; k0 += 32) {
        #pragma unroll
        for (int rr = 0; rr < 128; rr += 64) {
            int m = m0 + sr + rr;
            short8 pk = {};
            if (m < M) pk = *(const short8*)(A + (long)m * 256 + k0 + sc);
            *(short8*)(As + (sr + rr) * 40 + sc) = pk;
        }
        *(short8*)(Bs + sr * 40 + sc) =
            *(const short8*)(W + (long)(n0 + sr) * 256 + k0 + sc);
        __syncthreads();

        const int krow = (ln >> 4) * 8;
        short8 af[2], bfr[4];
        #pragma unroll
        for (int i = 0; i < 2; i++)
            af[i] = *(const short8*)(As + (w * 32 + i * 16 + (ln & 15)) * 40 + krow);
        #pragma unroll
        for (int j = 0; j < 4; j++)
            bfr[j] = *(const short8*)(Bs + (j * 16 + (ln & 15)) * 40 + krow);
        #pragma unroll
        for (int i = 0; i < 2; i++)
            #pragma unroll
            for (int j = 0; j < 4; j++)
                acc[i][j] = __builtin_amdgcn_mfma_f32_16x16x32_bf16(af[i], bfr[j], acc[i][j], 0, 0, 0);
        __syncthreads();
    }
}

// ---------------- fused gemm1 (z=0) + gemm2/3 (z=1) ----------------
// z=0: vproj(bf16,*zeta) = v_bf @ Wv^T + b_value ; N=256 (832 blocks of grid.x)
// z=1: oa(f32)[NTOK][384] = q_bf @ [Wo;Wa]^T + [b_off;b_attn] ; N=384 (1248 blocks)
// XCD-bijective swizzle: bid%8 = XCD; each XCD owns contiguous M-panels, all N-tiles
// of a panel on the same XCD -> A fetched once from HBM per XCD.
__global__ __launch_bounds__(256) void gemm_fused_k(
    const ushort_t* __restrict__ q_bf, const ushort_t* __restrict__ v_bf,
    const ushort_t* __restrict__ Wv,   const ushort_t* __restrict__ WoWa,
    const float* __restrict__ b_value, const float* __restrict__ b_off,
    const float* __restrict__ b_attn,  const float* __restrict__ zeta,
    ushort_t* __restrict__ vproj, float* __restrict__ oa)
{
    __shared__ __align__(16) ushort_t As[128 * 40];
    __shared__ __align__(16) ushort_t Bs[64 * 40];

    const int z = blockIdx.z;
    const int bid = blockIdx.x;
    int x, y;
    if (z == 0) {
        if (bid >= 832) return;                 // whole block, before any barrier
        int id = (bid & 7) * 104 + (bid >> 3);  // 832 = 8*104, bijective
        x = id >> 2; y = id & 3;                // 208 x-panels, 4 n-tiles
    } else {
        int id = (bid & 7) * 156 + (bid >> 3);  // 1248 = 8*156, bijective
        x = id / 6; y = id - x * 6;             // 208 x-panels, 6 n-tiles
    }
    const int m0 = x * 128;
    const int n0 = y * 64;
    const ushort_t* A = z ? q_bf : v_bf;
    const ushort_t* W = z ? WoWa : Wv;

    float4_t acc[2][4] = {};
    gemm_tile(A, W, m0, n0, NTOK, As, Bs, acc);

    const int tid = threadIdx.x;
    const int w = tid >> 6, ln = tid & 63;
    const int col = ln & 15;
    const int rq  = (ln >> 4) * 4;
    #pragma unroll
    for (int j = 0; j < 4; j++) {
        int n = n0 + j * 16 + col;
        if (z == 0) {
            float bz = b_value[n];
            float zz = zeta[n & 31];
            #pragma unroll
            for (int i = 0; i < 2; i++) {
                #pragma unroll
                for (int r = 0; r < 4; r++) {
                    int m = m0 + w * 32 + i * 16 + rq + r;
                    if (m < NTOK) vproj[(long)m * 256 + n] = f2b((acc[i][j][r] + bz) * zz);
                }
            }
        } else {
            float bz = (n < 256) ? b_off[n] : b_attn[n - 256];
            #pragma unroll
            for (int i = 0; i < 2; i++) {
                #pragma unroll
                for (int r = 0; r < 4; r++) {
                    int m = m0 + w * 32 + i * 16 + rq + r;
                    if (m < NTOK) oa[(long)m * 384 + n] = acc[i][j][r] + bz;
                }
            }
        }
    }
}

// ---------------- final out-projection gemm (f32 out) ----------------
__global__ __launch_bounds__(256) void gemm_out_k(
    const ushort_t* __restrict__ A,     // outpre [NTOK][256] bf16
    const ushort_t* __restrict__ W,     // Wout_bf [256][256]
    const float* __restrict__ bias,     // [256]
    float* __restrict__ C)              // [NTOK][256] f32
{
    __shared__ __align__(16) ushort_t As[128 * 40];
    __shared__ __align__(16) ushort_t Bs[64 * 40];

    const int bid = blockIdx.x;                 // 832
    int id = (bid & 7) * 104 + (bid >> 3);
    const int m0 = (id >> 2) * 128;
    const int n0 = (id & 3) * 64;

    float4_t acc[2][4] = {};
    gemm_tile(A, W, m0, n0, NTOK, As, Bs, acc);

    const int tid = threadIdx.x;
    const int w = tid >> 6, ln = tid & 63;
    const int col = ln & 15;
    const int rq  = (ln >> 4) * 4;
    #pragma unroll
    for (int j = 0; j < 4; j++) {
        int n = n0 + j * 16 + col;
        float bz = bias[n];
        #pragma unroll
        for (int i = 0; i < 2; i++) {
            #pragma unroll
            for (int r = 0; r < 4; r++) {
                int m = m0 + w * 32 + i * 16 + rq + r;
                if (m < NTOK) C[(long)m * 256 + n] = acc[i][j][r] + bz;
            }
        }
    }
}

// ---------------- sampler: two-phase, bf16 gathers ----------------
// One block per token (XCD-swizzled), 512 threads = 8 waves.
// Phase 1 (128 thr): softmax + masked bilinear weights + clamped byte offsets (<<9,
//   bf16 rows are 512 B) -> 4KB LDS.
// Phase 2: lane (h=tid>>6, g=ln&7 4-ch group, s=ln>>3 point slot): 2 iters x
//   (LDS b128 params + 4x 8B bf16 gathers + bit-expand + 16 FMA).
__global__ __launch_bounds__(512) void sample_k(
    const float* __restrict__ refp,    // [NTOK][4][2]
    const ushort_t* __restrict__ v,    // [NTOK][256] bf16 (b-major)
    const float* __restrict__ oa,      // [NTOK][384]: 256 off then 128 logits
    ushort_t* __restrict__ outp)       // [NTOK][256] bf16
{
    __shared__ int   p_ofs[128][4];
    __shared__ float p_w[128][4];
    const int bid = blockIdx.x;
    const int t = (bid & 7) * CHUNK + (bid >> 3);
    if (t >= NTOK) return;             // whole block exits (before barrier)
    const int b = (t >= LQ) ? 1 : 0;
    const int tid = threadIdx.x;

    if (tid < 128) {
        const int h = tid >> 4, pi = tid & 15;
        const int lvl = pi >> 2;
        const int Wi  = (lvl == 0) ? 100 : (lvl == 1) ? 50 : (lvl == 2) ? 25 : 13;
        const int st  = (lvl == 0) ? 0 : (lvl == 1) ? 10000 : (lvl == 2) ? 12500 : 13125;
        const float Wf = (float)Wi;

        float lg = oa[(long)t * 384 + 256 + h * 16 + pi];
        float smax = lg;
        #pragma unroll
        for (int d = 1; d < 16; d <<= 1) smax = fmaxf(smax, __shfl_xor(smax, d, 64));
        float ex = __expf(lg - smax);
        float sm = ex;
        #pragma unroll
        for (int d = 1; d < 16; d <<= 1) sm += __shfl_xor(sm, d, 64);
        const float a = ex / sm;

        float ox = oa[(long)t * 384 + h * 32 + pi * 2];
        float oy = oa[(long)t * 384 + h * 32 + pi * 2 + 1];
        float rx = refp[(long)t * 8 + lvl * 2];
        float ry = refp[(long)t * 8 + lvl * 2 + 1];

        float x = rx * Wf + ox - 0.5f;
        float y = ry * Wf + oy - 0.5f;
        float xf = floorf(x), yf = floorf(y);
        float wx = x - xf, wy = y - yf;
        int x0 = (int)xf, y0 = (int)yf;

        float mx0 = ((unsigned)x0       < (unsigned)Wi) ? (1.f - wx) : 0.f;
        float mx1 = ((unsigned)(x0 + 1) < (unsigned)Wi) ? wx         : 0.f;
        float my0 = ((unsigned)y0       < (unsigned)Wi) ? (1.f - wy) * a : 0.f;
        float my1 = ((unsigned)(y0 + 1) < (unsigned)Wi) ? wy * a         : 0.f;
        int x0c = min(max(x0, 0), Wi - 1);
        int x1c = min(max(x0 + 1, 0), Wi - 1);
        int y0c = min(max(y0, 0), Wi - 1);
        int y1c = min(max(y0 + 1, 0), Wi - 1);

        int r0 = st + y0c * Wi, r1 = st + y1c * Wi;
        p_ofs[tid][0] = (r0 + x0c) << 9;   // *256 elem *2 B (bf16)
        p_ofs[tid][1] = (r0 + x1c) << 9;
        p_ofs[tid][2] = (r1 + x0c) << 9;
        p_ofs[tid][3] = (r1 + x1c) << 9;
        p_w[tid][0] = mx0 * my0;
        p_w[tid][1] = mx1 * my0;
        p_w[tid][2] = mx0 * my1;
        p_w[tid][3] = mx1 * my1;
    }
    __syncthreads();

    const int h = tid >> 6, ln = tid & 63, g = ln & 7, s = ln >> 3;
    const char* vb = (const char*)(v + ((long)b * LQ) * 256 + h * 32 + g * 4);
    float4_t acc = {0.f, 0.f, 0.f, 0.f};

    #pragma unroll
    for (int it = 0; it < 2; it++) {
        const int task = h * 16 + it * 8 + s;
        int4     o  = *(const int4*)p_ofs[task];
        float4_t w4 = *(const float4_t*)p_w[task];
        uint2_t u00 = *(const uint2_t*)(vb + o.x);
        uint2_t u01 = *(const uint2_t*)(vb + o.y);
        uint2_t u10 = *(const uint2_t*)(vb + o.z);
        uint2_t u11 = *(const uint2_t*)(vb + o.w);
        // 2 bf16 per dword: lo -> <<16, hi -> &0xffff0000
        acc[0] += w4.x * __uint_as_float(u00.x << 16)
                + w4.y * __uint_as_float(u01.x << 16)
                + w4.z * __uint_as_float(u10.x << 16)
                + w4.w * __uint_as_float(u11.x << 16);
        acc[1] += w4.x * __uint_as_float(u00.x & 0xffff0000u)
                + w4.y * __uint_as_float(u01.x & 0xffff0000u)
                + w4.z * __uint_as_float(u10.x & 0xffff0000u)
                + w4.w * __uint_as_float(u11.x & 0xffff0000u);
        acc[2] += w4.x * __uint_as_float(u00.y << 16)
                + w4.y * __uint_as_float(u01.y << 16)
                + w4.z * __uint_as_float(u10.y << 16)
                + w4.w * __uint_as_float(u11.y << 16);
        acc[3] += w4.x * __uint_as_float(u00.y & 0xffff0000u)
                + w4.y * __uint_as_float(u01.y & 0xffff0000u)
                + w4.z * __uint_as_float(u10.y & 0xffff0000u)
                + w4.w * __uint_as_float(u11.y & 0xffff0000u);
    }

    #pragma unroll
    for (int d = 32; d >= 8; d >>= 1) {
        acc.x += __shfl_down(acc.x, d, 64);
        acc.y += __shfl_down(acc.y, d, 64);
        acc.z += __shfl_down(acc.z, d, 64);
        acc.w += __shfl_down(acc.w, d, 64);
    }
    if (s == 0) {
        ushort4 o;
        o.x = f2b(acc.x); o.y = f2b(acc.y); o.z = f2b(acc.z); o.w = f2b(acc.w);
        *(ushort4*)(outp + (long)t * 256 + h * 32 + g * 4) = o;
    }
}

extern "C" void kernel_launch(void* const* d_in, const int* in_sizes, int n_in,
                              void* d_out, int out_size, void* d_ws, size_t ws_size,
                              hipStream_t stream)
{
    // inputs: 0 query, 1 reference_points, 2 value, 3 spatial_shapes(int32),
    // 4 W_value, 5 b_value, 6 W_off, 7 b_off, 8 W_attn, 9 b_attn, 10 W_out, 11 b_out, 12 zeta
    char* ws = (char*)d_ws;
    ushort_t* vproj   = (ushort_t*)ws;                                   // NE bf16
    float*    oa      = (float*)(ws + (long)NE * 2);                     // NTOK*384 f32
    ushort_t* q_bf    = (ushort_t*)(ws + (long)NE * 2 + (long)NTOK * 1536);
    ushort_t* outpre  = q_bf;           // overlay: q dead after fused gemm (stream-ordered)
    ushort_t* v_bf    = q_bf + NE;
    ushort_t* Wv_bf   = v_bf + NE;
    ushort_t* WoWa_bf = Wv_bf + 65536;  // 384 contiguous rows: W_off(256) + W_attn(128)
    ushort_t* Wout_bf = WoWa_bf + 98304;
    // total: 13.61 + 40.84 + 13.61 + 13.61 + 0.46 MB = 82.14 MB (< r8's 82.3)

    cvt_k<<<1024, 256, 0, stream>>>(
        (const float*)d_in[0], (const float*)d_in[2], (const float*)d_in[4],
        (const float*)d_in[6], (const float*)d_in[8], (const float*)d_in[10],
        q_bf, v_bf, Wv_bf, WoWa_bf, Wout_bf);

    gemm_fused_k<<<dim3(1248, 1, 2), 256, 0, stream>>>(
        q_bf, v_bf, Wv_bf, WoWa_bf,
        (const float*)d_in[5], (const float*)d_in[7], (const float*)d_in[9],
        (const float*)d_in[12], vproj, oa);

    sample_k<<<8 * CHUNK, 512, 0, stream>>>(
        (const float*)d_in[1], vproj, oa, outpre);   // outpre overlays q_bf (dead)

    gemm_out_k<<<832, 256, 0, stream>>>(
        outpre, Wout_bf, (const float*)d_in[11], (float*)d_out);
}

// Round 2
// 224.464 us; speedup vs baseline: 1.1871x; 1.0781x over previous
//
#include <hip/hip_runtime.h>

// SparseMSDeformableAttention MI355X — round 10.
// r9 post-mortem: sample_k is VALU-issue-bound (FETCH halved, dur -5%): 30% of
// lane-slots idle in phase1 (128/512 thr), 24-op shuffle tree, 8-load/thread MLP.
// GEMMs still reg-staged (6 ops + VGPR roundtrip per k-step).
//  - sample_k: 4 tokens/block (26588=4*6647, no tail); phase1 all-thread;
//    phase2 128 thr/token x 8 pts/thread, single shfl_down(8) reduce.
//  - gemm_tile: global_load_lds(16B) staging, linear LDS stride 32 ushorts
//    (64B rows: b128 frag reads touch each bank exactly 8x = conflict-free min).
//    OOB tail rows read allocated ws garbage -> masked at C store.

#define LQ    13294
#define NTOK  26588
#define NE    6806528     // NTOK*256

typedef unsigned short ushort_t;
typedef __attribute__((ext_vector_type(8))) short short8;
typedef __attribute__((ext_vector_type(4))) float float4_t;
typedef __attribute__((ext_vector_type(2))) unsigned int uint2_t;

__device__ __forceinline__ ushort_t f2b(float f) {
    unsigned int x = __float_as_uint(f);
    return (ushort_t)((x + 0x7fffu + ((x >> 16) & 1u)) >> 16);   // RNE
}

__device__ __forceinline__ void gload16(const void* g, void* l) {
    __builtin_amdgcn_global_load_lds(
        (const __attribute__((address_space(1))) unsigned int*)g,
        (__attribute__((address_space(3))) unsigned int*)l, 16, 0, 0);
}

// ---------------- bulk f32 -> bf16 convert ----------------
__device__ __forceinline__ void cvt_seg(const float* __restrict__ s,
                                        ushort_t* __restrict__ d,
                                        int n4, int gid, int stride) {
    const float4_t* s4 = (const float4_t*)s;
    for (int i = gid; i < n4; i += stride) {
        float4_t f = s4[i];
        ushort4 o;
        o.x = f2b(f.x); o.y = f2b(f.y); o.z = f2b(f.z); o.w = f2b(f.w);
        *(ushort4*)(d + (long)i * 4) = o;
    }
}

__global__ __launch_bounds__(256) void cvt_k(
    const float* q, const float* v, const float* Wv, const float* Wo,
    const float* Wa, const float* Wout,
    ushort_t* q_bf, ushort_t* v_bf, ushort_t* Wv_bf, ushort_t* WoWa_bf,
    ushort_t* Wout_bf)
{
    const int gid = blockIdx.x * 256 + threadIdx.x;
    const int stride = gridDim.x * 256;
    cvt_seg(q,    q_bf,            NE / 4,     gid, stride);
    cvt_seg(v,    v_bf,            NE / 4,     gid, stride);
    cvt_seg(Wv,   Wv_bf,           65536 / 4,  gid, stride);
    cvt_seg(Wo,   WoWa_bf,         65536 / 4,  gid, stride);   // rows 0..255
    cvt_seg(Wa,   WoWa_bf + 65536, 32768 / 4,  gid, stride);   // rows 256..383
    cvt_seg(Wout, Wout_bf,         65536 / 4,  gid, stride);
}

// ---------------- bf16 MFMA tile body: global_load_lds staging ----------
// 256 threads = 4 waves; tile 128(M) x 64(N), K-tile 32; LDS linear stride 32.
// Stage per k-step: 2 A-gll + 1 B-gll per wave (16 rows x 64B each, lane l
// writes lds_base + l*16: row l>>2, colbyte (l&3)*16 — exactly linear).
// Frag maps (r7-validated): A[m=ln&15][k=(ln>>4)*8+j]; B=W[n=ln&15][k];
// D col=ln&15 (n), row=(ln>>4)*4+r (m).
__device__ __forceinline__ void gemm_tile(
    const ushort_t* __restrict__ A,     // [>=m0+128][256] bf16 (OOB rows ok)
    const ushort_t* __restrict__ W,     // [>=n0+64][256] bf16
    int m0, int n0,
    ushort_t* As, ushort_t* Bs, float4_t acc[2][4])
{
    const int tid = threadIdx.x;
    const int w  = tid >> 6;
    const int ln = tid & 63;
    const int lr = ln >> 2;             // row 0..15 within 16-row group
    const int lc = (ln & 3) * 8;        // ushort col {0,8,16,24}

    ushort_t* lA0 = As + (w * 2 + 0) * 512;         // rows w*32 + 0..15
    ushort_t* lA1 = As + (w * 2 + 1) * 512;         // rows w*32 + 16..31
    ushort_t* lB  = Bs + w * 512;                   // rows w*16 + 0..15
    const ushort_t* gA0 = A + (long)(m0 + w * 32 + lr) * 256 + lc;
    const ushort_t* gA1 = gA0 + 16 * 256;
    const ushort_t* gB  = W + (long)(n0 + w * 16 + lr) * 256 + lc;

    const int krow = (ln >> 4) * 8;
    const int fr   = ln & 15;

    for (int k0 = 0; k0 < 256; k0 += 32) {
        gload16(gA0 + k0, lA0);
        gload16(gA1 + k0, lA1);
        gload16(gB  + k0, lB);
        __syncthreads();

        short8 af[2], bfr[4];
        #pragma unroll
        for (int i = 0; i < 2; i++)
            af[i] = *(const short8*)(As + (w * 32 + i * 16 + fr) * 32 + krow);
        #pragma unroll
        for (int j = 0; j < 4; j++)
            bfr[j] = *(const short8*)(Bs + (j * 16 + fr) * 32 + krow);
        #pragma unroll
        for (int i = 0; i < 2; i++)
            #pragma unroll
            for (int j = 0; j < 4; j++)
                acc[i][j] = __builtin_amdgcn_mfma_f32_16x16x32_bf16(af[i], bfr[j], acc[i][j], 0, 0, 0);
        __syncthreads();
    }
}

// ---------------- fused gemm1 (z=0) + gemm2/3 (z=1) ----------------
__global__ __launch_bounds__(256) void gemm_fused_k(
    const ushort_t* __restrict__ q_bf, const ushort_t* __restrict__ v_bf,
    const ushort_t* __restrict__ Wv,   const ushort_t* __restrict__ WoWa,
    const float* __restrict__ b_value, const float* __restrict__ b_off,
    const float* __restrict__ b_attn,  const float* __restrict__ zeta,
    ushort_t* __restrict__ vproj, float* __restrict__ oa)
{
    __shared__ __align__(16) ushort_t As[128 * 32];
    __shared__ __align__(16) ushort_t Bs[64 * 32];

    const int z = blockIdx.z;
    const int bid = blockIdx.x;
    int x, y;
    if (z == 0) {
        if (bid >= 832) return;                 // whole block, before any barrier
        int id = (bid & 7) * 104 + (bid >> 3);  // 832 = 8*104, bijective
        x = id >> 2; y = id & 3;
    } else {
        int id = (bid & 7) * 156 + (bid >> 3);  // 1248 = 8*156, bijective
        x = id / 6; y = id - x * 6;
    }
    const int m0 = x * 128;
    const int n0 = y * 64;

    float4_t acc[2][4] = {};
    gemm_tile(z ? q_bf : v_bf, z ? WoWa : Wv, m0, n0, As, Bs, acc);

    const int tid = threadIdx.x;
    const int w = tid >> 6, ln = tid & 63;
    const int col = ln & 15;
    const int rq  = (ln >> 4) * 4;
    #pragma unroll
    for (int j = 0; j < 4; j++) {
        int n = n0 + j * 16 + col;
        if (z == 0) {
            float bz = b_value[n];
            float zz = zeta[n & 31];
            #pragma unroll
            for (int i = 0; i < 2; i++) {
                #pragma unroll
                for (int r = 0; r < 4; r++) {
                    int m = m0 + w * 32 + i * 16 + rq + r;
                    if (m < NTOK) vproj[(long)m * 256 + n] = f2b((acc[i][j][r] + bz) * zz);
                }
            }
        } else {
            float bz = (n < 256) ? b_off[n] : b_attn[n - 256];
            #pragma unroll
            for (int i = 0; i < 2; i++) {
                #pragma unroll
                for (int r = 0; r < 4; r++) {
                    int m = m0 + w * 32 + i * 16 + rq + r;
                    if (m < NTOK) oa[(long)m * 384 + n] = acc[i][j][r] + bz;
                }
            }
        }
    }
}

// ---------------- final out-projection gemm (f32 out) ----------------
__global__ __launch_bounds__(256) void gemm_out_k(
    const ushort_t* __restrict__ A,     // outpre [NTOK][256] bf16
    const ushort_t* __restrict__ W,     // Wout_bf [256][256]
    const float* __restrict__ bias,     // [256]
    float* __restrict__ C)              // [NTOK][256] f32
{
    __shared__ __align__(16) ushort_t As[128 * 32];
    __shared__ __align__(16) ushort_t Bs[64 * 32];

    const int bid = blockIdx.x;                 // 832
    int id = (bid & 7) * 104 + (bid >> 3);
    const int m0 = (id >> 2) * 128;
    const int n0 = (id & 3) * 64;

    float4_t acc[2][4] = {};
    gemm_tile(A, W, m0, n0, As, Bs, acc);

    const int tid = threadIdx.x;
    const int w = tid >> 6, ln = tid & 63;
    const int col = ln & 15;
    const int rq  = (ln >> 4) * 4;
    #pragma unroll
    for (int j = 0; j < 4; j++) {
        int n = n0 + j * 16 + col;
        float bz = bias[n];
        #pragma unroll
        for (int i = 0; i < 2; i++) {
            #pragma unroll
            for (int r = 0; r < 4; r++) {
                int m = m0 + w * 32 + i * 16 + rq + r;
                if (m < NTOK) C[(long)m * 256 + n] = acc[i][j][r] + bz;
            }
        }
    }
}

// ---------------- sampler: 4 tokens/block, two-phase ----------------
// Phase 1 (all 512 thr = 4 tok x 128 (h,p) workers): softmax + masked bilinear
//   weights + clamped byte offsets -> 16KB LDS.
// Phase 2 (128 thr/token: h(8) x s(2) x g(8)): 8 points/thread, 4x 8B bf16
//   gathers + unpack + FMA per point; single shfl_down(8) pair-reduce.
__global__ __launch_bounds__(512) void sample_k(
    const float* __restrict__ refp,    // [NTOK][4][2]
    const ushort_t* __restrict__ v,    // [NTOK][256] bf16 (b-major)
    const float* __restrict__ oa,      // [NTOK][384]: 256 off then 128 logits
    ushort_t* __restrict__ outp)       // [NTOK][256] bf16
{
    __shared__ int   p_ofs[512][4];
    __shared__ float p_w[512][4];
    const int tid = threadIdx.x;
    const int t0 = blockIdx.x * 4;     // 26588 = 4*6647 exactly, no tail

    {   // ---- phase 1 ----
        const int tok = tid >> 7, wt = tid & 127;
        const long t = t0 + tok;
        const int h = wt >> 4, pi = wt & 15;
        const int lvl = pi >> 2;
        const int Wi  = (lvl == 0) ? 100 : (lvl == 1) ? 50 : (lvl == 2) ? 25 : 13;
        const int st  = (lvl == 0) ? 0 : (lvl == 1) ? 10000 : (lvl == 2) ? 12500 : 13125;
        const float Wf = (float)Wi;

        float lg = oa[t * 384 + 256 + h * 16 + pi];
        float smax = lg;
        #pragma unroll
        for (int d = 1; d < 16; d <<= 1) smax = fmaxf(smax, __shfl_xor(smax, d, 64));
        float ex = __expf(lg - smax);
        float sm = ex;
        #pragma unroll
        for (int d = 1; d < 16; d <<= 1) sm += __shfl_xor(sm, d, 64);
        const float a = ex / sm;

        float ox = oa[t * 384 + h * 32 + pi * 2];
        float oy = oa[t * 384 + h * 32 + pi * 2 + 1];
        float rx = refp[t * 8 + lvl * 2];
        float ry = refp[t * 8 + lvl * 2 + 1];

        float x = rx * Wf + ox - 0.5f;
        float y = ry * Wf + oy - 0.5f;
        float xf = floorf(x), yf = floorf(y);
        float wx = x - xf, wy = y - yf;
        int x0 = (int)xf, y0 = (int)yf;

        float mx0 = ((unsigned)x0       < (unsigned)Wi) ? (1.f - wx) : 0.f;
        float mx1 = ((unsigned)(x0 + 1) < (unsigned)Wi) ? wx         : 0.f;
        float my0 = ((unsigned)y0       < (unsigned)Wi) ? (1.f - wy) * a : 0.f;
        float my1 = ((unsigned)(y0 + 1) < (unsigned)Wi) ? wy * a         : 0.f;
        int x0c = min(max(x0, 0), Wi - 1);
        int x1c = min(max(x0 + 1, 0), Wi - 1);
        int y0c = min(max(y0, 0), Wi - 1);
        int y1c = min(max(y0 + 1, 0), Wi - 1);

        int r0 = st + y0c * Wi, r1 = st + y1c * Wi;
        p_ofs[tid][0] = (r0 + x0c) << 9;   // *256 elem *2 B (bf16)
        p_ofs[tid][1] = (r0 + x1c) << 9;
        p_ofs[tid][2] = (r1 + x0c) << 9;
        p_ofs[tid][3] = (r1 + x1c) << 9;
        p_w[tid][0] = mx0 * my0;
        p_w[tid][1] = mx1 * my0;
        p_w[tid][2] = mx0 * my1;
        p_w[tid][3] = mx1 * my1;
    }
    __syncthreads();

    // ---- phase 2 ----
    const int tok = tid >> 7, wt = tid & 127;
    const long t = t0 + tok;
    const int b = (t >= LQ) ? 1 : 0;
    const int h = wt >> 4, s = (wt >> 3) & 1, g = wt & 7;
    const char* vb = (const char*)(v + ((long)b * LQ) * 256 + h * 32 + g * 4);
    const int base = tok * 128 + h * 16 + s * 8;
    float4_t acc = {0.f, 0.f, 0.f, 0.f};

    #pragma unroll 4
    for (int p = 0; p < 8; p++) {
        int4     o  = *(const int4*)p_ofs[base + p];
        float4_t w4 = *(const float4_t*)p_w[base + p];
        uint2_t u00 = *(const uint2_t*)(vb + o.x);
        uint2_t u01 = *(const uint2_t*)(vb + o.y);
        uint2_t u10 = *(const uint2_t*)(vb + o.z);
        uint2_t u11 = *(const uint2_t*)(vb + o.w);
        acc[0] += w4.x * __uint_as_float(u00.x << 16)
                + w4.y * __uint_as_float(u01.x << 16)
                + w4.z * __uint_as_float(u10.x << 16)
                + w4.w * __uint_as_float(u11.x << 16);
        acc[1] += w4.x * __uint_as_float(u00.x & 0xffff0000u)
                + w4.y * __uint_as_float(u01.x & 0xffff0000u)
                + w4.z * __uint_as_float(u10.x & 0xffff0000u)
                + w4.w * __uint_as_float(u11.x & 0xffff0000u);
        acc[2] += w4.x * __uint_as_float(u00.y << 16)
                + w4.y * __uint_as_float(u01.y << 16)
                + w4.z * __uint_as_float(u10.y << 16)
                + w4.w * __uint_as_float(u11.y << 16);
        acc[3] += w4.x * __uint_as_float(u00.y & 0xffff0000u)
                + w4.y * __uint_as_float(u01.y & 0xffff0000u)
                + w4.z * __uint_as_float(u10.y & 0xffff0000u)
                + w4.w * __uint_as_float(u11.y & 0xffff0000u);
    }

    acc.x += __shfl_down(acc.x, 8, 64);
    acc.y += __shfl_down(acc.y, 8, 64);
    acc.z += __shfl_down(acc.z, 8, 64);
    acc.w += __shfl_down(acc.w, 8, 64);

    if (s == 0) {
        ushort4 o;
        o.x = f2b(acc.x); o.y = f2b(acc.y); o.z = f2b(acc.z); o.w = f2b(acc.w);
        *(ushort4*)(outp + t * 256 + h * 32 + g * 4) = o;
    }
}

extern "C" void kernel_launch(void* const* d_in, const int* in_sizes, int n_in,
                              void* d_out, int out_size, void* d_ws, size_t ws_size,
                              hipStream_t stream)
{
    // inputs: 0 query, 1 reference_points, 2 value, 3 spatial_shapes(int32),
    // 4 W_value, 5 b_value, 6 W_off, 7 b_off, 8 W_attn, 9 b_attn, 10 W_out, 11 b_out, 12 zeta
    char* ws = (char*)d_ws;
    ushort_t* vproj   = (ushort_t*)ws;                                   // NE bf16
    float*    oa      = (float*)(ws + (long)NE * 2);                     // NTOK*384 f32
    ushort_t* q_bf    = (ushort_t*)(ws + (long)NE * 2 + (long)NTOK * 1536);
    ushort_t* outpre  = q_bf;           // overlay: q dead after fused gemm
    ushort_t* v_bf    = q_bf + NE;
    ushort_t* Wv_bf   = v_bf + NE;
    ushort_t* WoWa_bf = Wv_bf + 65536;  // 384 rows: W_off(256) + W_attn(128)
    ushort_t* Wout_bf = WoWa_bf + 98304;

    cvt_k<<<1024, 256, 0, stream>>>(
        (const float*)d_in[0], (const float*)d_in[2], (const float*)d_in[4],
        (const float*)d_in[6], (const float*)d_in[8], (const float*)d_in[10],
        q_bf, v_bf, Wv_bf, WoWa_bf, Wout_bf);

    gemm_fused_k<<<dim3(1248, 1, 2), 256, 0, stream>>>(
        q_bf, v_bf, Wv_bf, WoWa_bf,
        (const float*)d_in[5], (const float*)d_in[7], (const float*)d_in[9],
        (const float*)d_in[12], vproj, oa);

    sample_k<<<6647, 512, 0, stream>>>(
        (const float*)d_in[1], vproj, oa, outpre);   // outpre overlays q_bf (dead)

    gemm_out_k<<<832, 256, 0, stream>>>(
        outpre, Wout_bf, (const float*)d_in[11], (float*)d_out);
}